// Round 1
// baseline (223.223 us; speedup 1.0000x reference)
//
#include <hip/hip_runtime.h>
#include <hip/hip_bf16.h>

// Problem constants (EmbDotSoftMax): B=4096, N_CITY=50, EC=128, VOCAB=40000
#define NC    50
#define EC    128
#define VOCAB 40000

// One block per batch row. 128 threads = 2 waves.
// Phase 1: x[b] -> LDS
// Phase 2: emb_pred[e] = dot(W[e,:], x[b]) + bias[e]  (thread e owns row e)
// Phase 3: scores[n] = dot(emb_pred, top_city_emb[b,n,:]) via 64-lane shfl reduce
// Phase 4: fill out row with 1e-6 (float4 stores, 160KB, the dominant cost)
// Phase 5: softmax over 50 + atomicAdd scatter into own row
__global__ __launch_bounds__(128)
void EmbDotSoftMax_fused_kernel(const float* __restrict__ x,
                                const float* __restrict__ emb,
                                const int*   __restrict__ ids,
                                const float* __restrict__ W,
                                const float* __restrict__ bias,
                                float*       __restrict__ out)
{
    const int b   = blockIdx.x;
    const int tid = threadIdx.x;

    __shared__ float4 x_s4[EC / 4];     // x[b] as float4
    __shared__ float  pred_s[EC];       // emb_pred
    __shared__ float  scores_s[NC];

    float* out_row = out + (size_t)b * VOCAB;

    // ---- Phase 1: stage x[b] ----
    if (tid < EC / 4) {
        x_s4[tid] = reinterpret_cast<const float4*>(x + (size_t)b * EC)[tid];
    }
    __syncthreads();

    // ---- Phase 2: emb_pred = x @ W^T + b  (thread tid computes element tid) ----
    {
        float acc = 0.0f;
        const float4* Wrow = reinterpret_cast<const float4*>(W + (size_t)tid * EC);
        #pragma unroll
        for (int k = 0; k < EC / 4; ++k) {
            float4 w4 = Wrow[k];
            float4 xv = x_s4[k];
            acc = fmaf(w4.x, xv.x, acc);
            acc = fmaf(w4.y, xv.y, acc);
            acc = fmaf(w4.z, xv.z, acc);
            acc = fmaf(w4.w, xv.w, acc);
        }
        pred_s[tid] = acc + bias[tid];
    }
    __syncthreads();

    // ---- Phase 3: scores. wave w handles cities [w*25, w*25+25) ----
    {
        const int w = tid >> 6;         // 0..1
        const int l = tid & 63;         // lane in wave
        const float p0 = pred_s[l];
        const float p1 = pred_s[l + 64];
        const float* erow = emb + (size_t)b * NC * EC;
        for (int i = 0; i < NC / 2; ++i) {
            const int n = w * (NC / 2) + i;
            const float* er = erow + (size_t)n * EC;
            float part = fmaf(p0, er[l], p1 * er[l + 64]);
            #pragma unroll
            for (int off = 32; off; off >>= 1)
                part += __shfl_xor(part, off);
            if (l == 0) scores_s[n] = part;
        }
    }

    // ---- Phase 4: fill this row with 1e-6 (coalesced float4) ----
    {
        const float4 fv = make_float4(1e-6f, 1e-6f, 1e-6f, 1e-6f);
        float4* out4 = reinterpret_cast<float4*>(out_row);   // VOCAB % 4 == 0, 16B-aligned rows
        for (int i = tid; i < VOCAB / 4; i += 128)
            out4[i] = fv;
    }
    __syncthreads();   // scores visible + fill stores drained before scatter

    // ---- Phase 5: softmax over 50 + scatter-add ----
    if (tid < NC) {
        float m = -1e30f;
        #pragma unroll
        for (int n = 0; n < NC; ++n) m = fmaxf(m, scores_s[n]);
        float sum = 0.0f;
        #pragma unroll
        for (int n = 0; n < NC; ++n) sum += __expf(scores_s[n] - m);
        const float p  = __expf(scores_s[tid] - m) / sum;
        const int   id = ids[(size_t)b * NC + tid];
        atomicAdd(out_row + id, p);    // atomics: intra-row duplicate ids
    }
}

extern "C" void kernel_launch(void* const* d_in, const int* in_sizes, int n_in,
                              void* d_out, int out_size, void* d_ws, size_t ws_size,
                              hipStream_t stream) {
    const float* x    = (const float*)d_in[0];
    const float* emb  = (const float*)d_in[1];
    const int*   ids  = (const int*)d_in[2];
    // d_in[3] = prob (zeros) — unused, output built from scratch
    const float* W    = (const float*)d_in[4];
    const float* bias = (const float*)d_in[5];
    float*       out  = (float*)d_out;

    const int B = in_sizes[0] / EC;    // 4096

    hipLaunchKernelGGL(EmbDotSoftMax_fused_kernel,
                       dim3(B), dim3(128), 0, stream,
                       x, emb, ids, W, bias, out);
}